// Round 18
// baseline (219.005 us; speedup 1.0000x reference)
//
#include <hip/hip_runtime.h>
#include <hip/hip_bf16.h>
#include <cmath>

constexpr int kCIN = 128, kHID = 256, kOUT = 349;
constexpr int kNT = 4, kET = 5;
constexpr int kN0 = 120000, kN1 = 40000, kN2 = 10000;
constexpr int kNSEG0 = kN1 * kET;   // 200000
constexpr int kNSEG1 = kN2 * kET;   // 50000
constexpr int kNSEG = kNSEG0 + kNSEG1;  // 250000

constexpr int kBinSegs = 512;                               // segments per bin
constexpr int kNBin0 = (kNSEG0 + kBinSegs - 1) / kBinSegs;  // 391
constexpr int kNBin1 = (kNSEG1 + kBinSegs - 1) / kBinSegs;  // 98
constexpr int kNBin  = kNBin0 + kNBin1;                     // 489
constexpr int kNBLK  = 256;                                 // partition blocks
constexpr int kSB    = 128;                                 // sort blocks per layer
constexpr int kGB    = (kN0 + 127) / 128;                   // gather blocks (128 rows/blk)
constexpr int kBinCap = 8192;                               // max edges/bin (validated r5/6)

typedef __bf16 bf16x8 __attribute__((ext_vector_type(8)));
typedef float f32x4 __attribute__((ext_vector_type(4)));
typedef float f32x2v __attribute__((ext_vector_type(2)));
typedef unsigned short ushort8v __attribute__((ext_vector_type(8)));

__device__ __forceinline__ unsigned short f2b(float f) {
    unsigned int b = __float_as_uint(f);
    unsigned int r = (b + 0x7FFFu + ((b >> 16) & 1u)) >> 16;
    return (unsigned short)r;
}
__device__ __forceinline__ float b2f(unsigned short u) {
    return __uint_as_float((unsigned int)u << 16);
}
__device__ __forceinline__ void gl2lds16(const void* g, void* l) {
    __builtin_amdgcn_global_load_lds(
        (const __attribute__((address_space(1))) void*)g,
        (__attribute__((address_space(3))) void*)l, 16, 0, 0);
}

// ---- fp8 e4m3fn helpers (HW cvt when available, manual fallback) -----------
__device__ __forceinline__ unsigned int f2e4m3(float f) {
#if __has_builtin(__builtin_amdgcn_cvt_pk_fp8_f32)
    return (unsigned int)(__builtin_amdgcn_cvt_pk_fp8_f32(f, f, 0, false) & 0xFF);
#else
    unsigned int sb = (__float_as_uint(f) >> 31) << 7;
    float m = fminf(fabsf(f), 448.f);
    unsigned int code;
    if (m < 0.015625f) {
        code = (unsigned int)__float2int_rn(m * 512.f);   // subnormal (incl. boundary)
    } else {
        unsigned int b = __float_as_uint(m);
        b = b + 0x7FFFF + ((b >> 20) & 1);                // RNE at 3-bit mantissa
        int e8 = (int)(b >> 23) - 120;
        if (e8 > 15) code = 0x7E;                          // saturate 448
        else code = ((unsigned int)e8 << 3) | ((b >> 20) & 7);
    }
    return sb | code;
#endif
}

__device__ __forceinline__ void e4m3x4_to_f32(unsigned int u, float* o4) {
#if __has_builtin(__builtin_amdgcn_cvt_pk_f32_fp8)
    f32x2v a = __builtin_amdgcn_cvt_pk_f32_fp8(u, false);
    f32x2v b = __builtin_amdgcn_cvt_pk_f32_fp8(u, true);
    o4[0] = a[0]; o4[1] = a[1]; o4[2] = b[0]; o4[3] = b[1];
#else
#pragma unroll
    for (int i = 0; i < 4; i++) {
        unsigned int c = (u >> (8 * i)) & 0xFF;
        unsigned int s = c >> 7, e = (c >> 3) & 15, mm = c & 7;
        float v;
        if (e == 0) v = (float)mm * 0.001953125f;
        else        v = __uint_as_float((e + 120u) << 23 | mm << 20);
        o4[i] = s ? -v : v;
    }
#endif
}

// ---------------- weight prep (both layers) + etype->u8, one kernel ---------
__global__ void k_prep(const float* __restrict__ relW0, const float* __restrict__ rootW0,
                       unsigned short* __restrict__ Bt0T,
                       const float* __restrict__ relW1, const float* __restrict__ rootW1,
                       unsigned short* __restrict__ Bt1T,
                       const int* __restrict__ etype, unsigned char* __restrict__ et8, int nET)
{
    constexpr int T0 = kNT * 256 * 768;
    constexpr int T1 = kNT * 384 * 1536;
    constexpr int TP = T0 + T1;
    int i = blockIdx.x * 256 + threadIdx.x;
    if (i < T0) {
        int g = i / (256 * 768);
        int rem = i - g * (256 * 768);
        int col = rem / 768;
        int k = rem - col * 768;
        float v = (k < 640) ? relW0[(size_t)k * 256 + col]
                            : rootW0[((size_t)g * 128 + (k - 640)) * 256 + col];
        Bt0T[i] = f2b(v);
    } else if (i < TP) {
        int ii = i - T0;
        int g = ii / (384 * 1536);
        int rem = ii - g * (384 * 1536);
        int col = rem / 1536;
        int k = rem - col * 1536;
        float v = 0.f;
        if (col < kOUT) v = (k < 1280) ? relW1[(size_t)k * kOUT + col]
                                       : rootW1[((size_t)g * 256 + (k - 1280)) * kOUT + col];
        Bt1T[ii] = f2b(v);
    } else {
        int k = i - TP;
        if (k < nET) et8[k] = (unsigned char)etype[k];
    }
}

// ---------------- fused pass A: gather | edge seg-codes + bin hist | nt hist -
__global__ __launch_bounds__(1024) void k_bincnt(
    const int* __restrict__ dst0, const int* __restrict__ eid0, int E0,
    const int* __restrict__ dst1, const int* __restrict__ eid1, int E1,
    const unsigned char* __restrict__ et8, int* __restrict__ cnts2d,
    int* __restrict__ seg32,
    const int* __restrict__ n_id, const int* __restrict__ ntype, int* __restrict__ ntcnts,
    const float* __restrict__ x0, const float* __restrict__ e1f,
    const float* __restrict__ e2f, const float* __restrict__ e3f,
    const int* __restrict__ lidx,
    unsigned short* __restrict__ h0b, unsigned char* __restrict__ h0f8,
    int* __restrict__ nt0)
{
    __shared__ int h[kNBin];
    const int tid = threadIdx.x;
    if (blockIdx.x < kGB) {
        // input gather: 128 rows per block, four rows per lane-group (MLP x4)
        int base = blockIdx.x * 128;
        int lane = tid & 31;
        int grp = tid >> 5;
        int r[4];
        const float* tab[4];
        int idx[4], ntv[4];
        bool ok[4];
#pragma unroll
        for (int k = 0; k < 4; k++) {
            r[k] = base + grp + k * 32;
            ok[k] = r[k] < kN0;
            int rr = ok[k] ? r[k] : kN0 - 1;
            int gid = n_id[rr];
            int nt = ntype[gid];
            int li = lidx[gid];
            const float* tb; int rows;
            if (nt == 0)      { tb = x0;  rows = 100000; }
            else if (nt == 1) { tb = e1f; rows = 50000; }
            else if (nt == 2) { tb = e2f; rows = 50000; }
            else              { tb = e3f; rows = 50000; }
            tab[k] = tb;
            idx[k] = li < rows ? li : rows - 1;
            ntv[k] = nt;
        }
        float4 v[4];
#pragma unroll
        for (int k = 0; k < 4; k++)
            v[k] = reinterpret_cast<const float4*>(tab[k] + (size_t)idx[k] * kCIN)[lane];
#pragma unroll
        for (int k = 0; k < 4; k++) {
            if (!ok[k]) continue;
            unsigned int q = f2e4m3(v[k].x) | (f2e4m3(v[k].y) << 8)
                           | (f2e4m3(v[k].z) << 16) | (f2e4m3(v[k].w) << 24);
            reinterpret_cast<unsigned int*>(h0f8 + (size_t)r[k] * kCIN)[lane] = q;
            if (r[k] < kN1) {   // bf16 copy only needed for gemm0's root slab
                ushort4 o;
                o.x = f2b(v[k].x); o.y = f2b(v[k].y); o.z = f2b(v[k].z); o.w = f2b(v[k].w);
                reinterpret_cast<ushort4*>(h0b + (size_t)r[k] * kCIN)[lane] = o;
            }
            if (lane == 0) nt0[r[k]] = ntv[k];
        }
    } else if (blockIdx.x < kGB + kNBLK) {
        int blk = blockIdx.x - kGB;
        for (int k = tid; k < kNBin; k += 1024) h[k] = 0;
        __syncthreads();
        int Etot = E0 + E1;
        int chunk = (Etot + kNBLK - 1) / kNBLK;
        int lo = blk * chunk;
        int hi = min(lo + chunk, Etot);
        for (int i = lo + tid; i < hi; i += 1024) {
            int c;
            if (i < E0) c = dst0[i] * kET + (int)et8[eid0[i]];
            else { int e = i - E0; c = kNBin0 * kBinSegs + dst1[e] * kET + (int)et8[eid1[e]]; }
            seg32[i] = c;
            atomicAdd(&h[c >> 9], 1);
        }
        __syncthreads();
        for (int k = tid; k < kNBin; k += 1024) cnts2d[(size_t)k * kNBLK + blk] = h[k];
    } else {
        int b = blockIdx.x - kGB - kNBLK;
        int layer = b >= kSB;
        int blk = b - layer * kSB;
        int M = layer ? kN2 : kN1;
        if (tid < 4) h[tid] = 0;
        __syncthreads();
        int chunk = (M + kSB - 1) / kSB;
        int lo = blk * chunk, hi = min(lo + chunk, M);
        for (int i = lo + tid; i < hi; i += 1024) atomicAdd(&h[ntype[n_id[i]]], 1);
        __syncthreads();
        if (tid < 4) ntcnts[(layer * 4 + tid) * kSB + blk] = h[tid];
    }
}

// ---------------- scans ------------------------------------------------------
__global__ void k_scan1(const int* __restrict__ cnt, int* __restrict__ excl,
                        int* __restrict__ blksum, int n)
{
    __shared__ int sm[1024];
    int i = blockIdx.x * 1024 + threadIdx.x;
    int v = (i < n) ? cnt[i] : 0;
    sm[threadIdx.x] = v;
    __syncthreads();
    for (int off = 1; off < 1024; off <<= 1) {
        int t = (threadIdx.x >= off) ? sm[threadIdx.x - off] : 0;
        __syncthreads();
        sm[threadIdx.x] += t;
        __syncthreads();
    }
    if (i < n) excl[i] = sm[threadIdx.x] - v;
    if (threadIdx.x == 1023) blksum[blockIdx.x] = sm[1023];
}

// block 0: scan blksum; block 1: segmented scan of ntcnts -> ntoffs + goff
__global__ __launch_bounds__(1024) void k_scan2(
    int* __restrict__ blksum, int nblk,
    const int* __restrict__ ntcnts, int* __restrict__ ntoffs,
    int* __restrict__ goff0, int* __restrict__ goff1)
{
    __shared__ int sm[1024];
    int tid = threadIdx.x;
    if (blockIdx.x == 0) {
        int v = (tid < nblk) ? blksum[tid] : 0;
        sm[tid] = v;
        __syncthreads();
        for (int off = 1; off < 1024; off <<= 1) {
            int t = (tid >= off) ? sm[tid - off] : 0;
            __syncthreads();
            sm[tid] += t;
            __syncthreads();
        }
        if (tid < nblk) blksum[tid] = sm[tid] - v;
    } else {
        int v = ntcnts[tid];
        sm[tid] = v;
        __syncthreads();
        for (int off = 1; off < 512; off <<= 1) {
            int t = 0;
            if ((tid & 511) >= off) t = sm[tid - off];
            __syncthreads();
            sm[tid] += t;
            __syncthreads();
        }
        int excl = sm[tid] - v;
        ntoffs[tid] = excl;
        if ((tid & 127) == 0) {
            int layer = tid >> 9;
            int t = (tid >> 7) & 3;
            if (layer == 0) goff0[t] = excl; else goff1[t] = excl;
        }
        if (tid == 0) { goff0[4] = kN1; goff1[4] = kN2; }
    }
}

// ---------------- pass B: place edges (seg32 streaming) + nt place ----------
__global__ __launch_bounds__(1024) void k_binplace(
    const int* __restrict__ src0, int E0,
    const int* __restrict__ src1, int E1,
    const int* __restrict__ seg32,
    const int* __restrict__ offs2d, const int* __restrict__ blksum,
    unsigned int* __restrict__ pairs,
    const int* __restrict__ nt0, const int* __restrict__ ntoffs,
    int* __restrict__ perm0, int* __restrict__ perm1)
{
    __shared__ int cur[kNBin];
    const int tid = threadIdx.x;
    if (blockIdx.x < kNBLK) {
        for (int k = tid; k < kNBin; k += 1024) {
            size_t li = (size_t)k * kNBLK + blockIdx.x;
            cur[k] = offs2d[li] + blksum[li >> 10];
        }
        __syncthreads();
        int Etot = E0 + E1;
        int chunk = (Etot + kNBLK - 1) / kNBLK;
        int lo = blockIdx.x * chunk;
        int hi = min(lo + chunk, Etot);
        for (int i = lo + tid; i < hi; i += 1024) {
            int c = seg32[i];
            int s = (i < E0) ? src0[i] : src1[i - E0];
            unsigned int pay = (unsigned int)s | ((unsigned int)(c & (kBinSegs - 1)) << 17);
            int p = atomicAdd(&cur[c >> 9], 1);
            pairs[p] = pay;
        }
    } else {
        int b = blockIdx.x - kNBLK;
        int layer = b >= kSB;
        int blk = b - layer * kSB;
        int M = layer ? kN2 : kN1;
        int* perm = layer ? perm1 : perm0;
        if (tid < 4) cur[tid] = ntoffs[(layer * 4 + tid) * kSB + blk];
        __syncthreads();
        int chunk = (M + kSB - 1) / kSB;
        int lo = blk * chunk, hi = min(lo + chunk, M);
        for (int i = lo + tid; i < hi; i += 1024) {
            int p = atomicAdd(&cur[nt0[i]], 1);
            perm[p] = i;
        }
    }
}

// ---------------- fused per-bin scatter + layer-0 segment-mean --------------
// hist+scan+scatter in LDS; layer-0 bins compute means directly (no global
// order round-trip); layer-1 bins persist starts/cnt/order for segreduce1.
__global__ __launch_bounds__(512) void k_binseg(
    const int* __restrict__ offs2d, const int* __restrict__ blksum, int Etot,
    const unsigned int* __restrict__ pairs,
    int* __restrict__ order, int* __restrict__ starts, int* __restrict__ cnt,
    const unsigned char* __restrict__ h0f8, unsigned short* __restrict__ meanb)
{
    __shared__ int h[kBinSegs];
    __shared__ int sc[kBinSegs];
    __shared__ int cur[kBinSegs];
    __shared__ int ordl[kBinCap];
    const int bin = blockIdx.x;
    const int tid = threadIdx.x;
    size_t bi = (size_t)bin * kNBLK;
    const int base = offs2d[bi] + blksum[bi >> 10];
    int end = Etot;
    if (bin + 1 < kNBin) {
        size_t ei = (size_t)(bin + 1) * kNBLK;
        end = offs2d[ei] + blksum[ei >> 10];
    }
    const int c = end - base;
    const unsigned int* pp = pairs + base;

    h[tid] = 0;
    __syncthreads();
    for (int j = tid; j < c; j += 512) atomicAdd(&h[pp[j] >> 17], 1);
    __syncthreads();
    sc[tid] = h[tid];
    __syncthreads();
    for (int off = 1; off < kBinSegs; off <<= 1) {
        int t = (tid >= off) ? sc[tid - off] : 0;
        __syncthreads();
        sc[tid] += t;
        __syncthreads();
    }
    cur[tid] = sc[tid] - h[tid];
    __syncthreads();
    for (int j = tid; j < c; j += 512) {
        unsigned int u = pp[j];
        int sl = (int)(u >> 17);
        int p = atomicAdd(&cur[sl], 1);
        if (p < kBinCap) ordl[p] = (int)(u & 0x1FFFFu);
    }
    __syncthreads();

    if (bin < kNBin0) {
        // layer-0: fp8 gather-mean straight from LDS order
        int seg_base = bin * kBinSegs;
        int seglim = min(kBinSegs, kNSEG0 - seg_base);
#pragma unroll 1
        for (int pass = 0; pass < 8; ++pass) {
            int srel = (tid >> 3) + pass * 64;
            if (srel >= seglim) continue;
            int lane = tid & 7;                 // 8 lanes x 16B = 128 fp8
            int st = sc[srel] - h[srel];
            int n = h[srel];
            const unsigned char* hp = h0f8 + (size_t)lane * 16;
            float a0[16], a1[16];
#pragma unroll
            for (int i = 0; i < 16; i++) { a0[i] = 0.f; a1[i] = 0.f; }
            int j = 0;
            for (; j + 2 <= n; j += 2) {
                int s0 = ordl[st + j];
                int s1 = ordl[st + j + 1];
                uint4 u0 = *reinterpret_cast<const uint4*>(hp + (size_t)s0 * kCIN);
                uint4 u1 = *reinterpret_cast<const uint4*>(hp + (size_t)s1 * kCIN);
                float d[16];
                e4m3x4_to_f32(u0.x, d); e4m3x4_to_f32(u0.y, d + 4);
                e4m3x4_to_f32(u0.z, d + 8); e4m3x4_to_f32(u0.w, d + 12);
#pragma unroll
                for (int i = 0; i < 16; i++) a0[i] += d[i];
                e4m3x4_to_f32(u1.x, d); e4m3x4_to_f32(u1.y, d + 4);
                e4m3x4_to_f32(u1.z, d + 8); e4m3x4_to_f32(u1.w, d + 12);
#pragma unroll
                for (int i = 0; i < 16; i++) a1[i] += d[i];
            }
            if (j < n) {
                int s0 = ordl[st + j];
                uint4 u0 = *reinterpret_cast<const uint4*>(hp + (size_t)s0 * kCIN);
                float d[16];
                e4m3x4_to_f32(u0.x, d); e4m3x4_to_f32(u0.y, d + 4);
                e4m3x4_to_f32(u0.z, d + 8); e4m3x4_to_f32(u0.w, d + 12);
#pragma unroll
                for (int i = 0; i < 16; i++) a0[i] += d[i];
            }
            float scv = 1.0f / fmaxf((float)n, 1.0f);
            ushort8v o0, o1;
#pragma unroll
            for (int i = 0; i < 8; i++) {
                o0[i] = f2b((a0[i] + a1[i]) * scv);
                o1[i] = f2b((a0[i + 8] + a1[i + 8]) * scv);
            }
            unsigned short* mp = meanb + (size_t)(seg_base + srel) * kCIN + lane * 16;
            *reinterpret_cast<ushort8v*>(mp) = o0;
            *reinterpret_cast<ushort8v*>(mp + 8) = o1;
        }
    } else {
        // layer-1: persist CSR for segreduce1 (runs after gemm0)
        int seg_rel = (bin - kNBin0) * kBinSegs;
        int abs_base = kNSEG0 + seg_rel;
        int seglim = kNSEG1 - seg_rel;
        if (tid < seglim) {
            starts[abs_base + tid] = base + (sc[tid] - h[tid]);
            cnt[abs_base + tid] = h[tid];
        }
        for (int j = tid; j < c; j += 512) order[base + j] = ordl[j];
    }
}

// ---------------- layer-1 segment-mean: fp8 gather (16B/lane) ---------------
template<int C>
__global__ __launch_bounds__(256) void k_segreduce8(
    const int* __restrict__ starts, const int* __restrict__ cnt,
    const int* __restrict__ order, const unsigned char* __restrict__ h8,
    unsigned short* __restrict__ mean, int nseg)
{
    constexpr int L = C / 16;
    constexpr int SPB = 256 / L;
    int sidx = blockIdx.x * SPB + threadIdx.x / L;
    if (sidx >= nseg) return;
    int lane = threadIdx.x % L;
    int st = starts[sidx];
    int n = cnt[sidx];
    const unsigned char* hp = h8 + (size_t)lane * 16;
    float a0[16], a1[16];
#pragma unroll
    for (int i = 0; i < 16; i++) { a0[i] = 0.f; a1[i] = 0.f; }
    int j = 0;
    for (; j + 2 <= n; j += 2) {
        int s0 = order[st + j + 0];
        int s1 = order[st + j + 1];
        uint4 u0 = *reinterpret_cast<const uint4*>(hp + (size_t)s0 * C);
        uint4 u1 = *reinterpret_cast<const uint4*>(hp + (size_t)s1 * C);
        float d[16];
        e4m3x4_to_f32(u0.x, d); e4m3x4_to_f32(u0.y, d + 4);
        e4m3x4_to_f32(u0.z, d + 8); e4m3x4_to_f32(u0.w, d + 12);
#pragma unroll
        for (int i = 0; i < 16; i++) a0[i] += d[i];
        e4m3x4_to_f32(u1.x, d); e4m3x4_to_f32(u1.y, d + 4);
        e4m3x4_to_f32(u1.z, d + 8); e4m3x4_to_f32(u1.w, d + 12);
#pragma unroll
        for (int i = 0; i < 16; i++) a1[i] += d[i];
    }
    if (j < n) {
        int s0 = order[st + j];
        uint4 u0 = *reinterpret_cast<const uint4*>(hp + (size_t)s0 * C);
        float d[16];
        e4m3x4_to_f32(u0.x, d); e4m3x4_to_f32(u0.y, d + 4);
        e4m3x4_to_f32(u0.z, d + 8); e4m3x4_to_f32(u0.w, d + 12);
#pragma unroll
        for (int i = 0; i < 16; i++) a0[i] += d[i];
    }
    float sc = 1.0f / fmaxf((float)n, 1.0f);
    ushort8v o0, o1;
#pragma unroll
    for (int i = 0; i < 8; i++) {
        o0[i] = f2b((a0[i] + a1[i]) * sc);
        o1[i] = f2b((a0[i + 8] + a1[i + 8]) * sc);
    }
    unsigned short* mp = mean + (size_t)sidx * C + lane * 16;
    *reinterpret_cast<ushort8v*>(mp) = o0;
    *reinterpret_cast<ushort8v*>(mp + 8) = o1;
}

// ---------------- sorted MFMA GEMM, NCB col-blocks, XCD-chunked blocks ------
template<int C, int BM, int BNF, int NCB, int WR, int WC, int RELU, int AF8, int OUTF32>
__global__ __launch_bounds__(256) void k_gemm_sorted(
    int M, int Nreal, int NpadK,
    const unsigned short* __restrict__ meanb,
    const unsigned short* __restrict__ hb,
    const unsigned char* __restrict__ hb8,
    const unsigned short* __restrict__ BtT,
    const float* __restrict__ rootb,
    const int* __restrict__ perm, const int* __restrict__ goff,
    float* __restrict__ outf, unsigned char* __restrict__ outf8)
{
    constexpr int K1 = kET * C;     // mean region
    constexpr int K  = K1 + C;      // + dense root slab
    constexpr int FM = BM / (16 * WR);
    constexpr int FN = BNF / (16 * WC);
    __shared__ __align__(16) char ldsA[BM * 128];
    __shared__ __align__(16) char ldsB[BNF * 128];

    int nwg = gridDim.x;
    int orig = blockIdx.x;
    int q = nwg >> 3, r8 = nwg & 7, x8 = orig & 7;
    int logical = (x8 < r8 ? x8 * (q + 1) : r8 * (q + 1) + (x8 - r8) * q) + (orig >> 3);
    int colb = logical % NCB;
    int t = logical / NCB;

    int g, row0s = 0, gend = 0;
    {
        int gs[5] = {goff[0], goff[1], goff[2], goff[3], goff[4]};
        int tb = 0;
        for (g = 0; g < 4; ++g) {
            int cg = gs[g + 1] - gs[g];
            int ntl = (cg + BM - 1) / BM;
            if (t < tb + ntl) { row0s = gs[g] + (t - tb) * BM; gend = gs[g + 1]; break; }
            tb += ntl;
        }
        if (g == 4) return;   // padding tile
    }
    const int rows_here = min(BM, gend - row0s);
    const unsigned short* BtG = BtT + (size_t)g * NpadK;

    const int tid = threadIdx.x;
    const int col0 = colb * BNF;
    const int wid = tid >> 6, lane = tid & 63;
    const int wrow = (wid / WC) * (BM / WR);
    const int wcol = (wid % WC) * (BNF / WC);
    const int lr = lane >> 3;
    const int kb = (lane & 7) * 16;

    f32x4 acc[FM][FN] = {};

    for (int k0 = 0; k0 < K; k0 += 64) {
        const bool inMean = (k0 < K1);
        const size_t kB = (size_t)k0 * 2;
        if (!AF8 || inMean) {
#pragma unroll
            for (int c2 = 0; c2 < BM / 32; ++c2) {
                int rb = (wid * (BM / 32) + c2) * 8;
                int r = rb + lr;
                int pr = perm[row0s + min(r, rows_here - 1)];
                const char* rowp = inMean
                    ? (const char*)(meanb + (size_t)pr * K1) + kB
                    : (const char*)(hb + (size_t)pr * C) + (kB - (size_t)K1 * 2);
                gl2lds16(rowp + (kb ^ ((r & 7) << 4)), &ldsA[rb * 128]);
            }
        } else {
#pragma unroll
            for (int c2 = 0; c2 < BM / 32; ++c2) {
                int rb = (wid * (BM / 32) + c2) * 8;
                int r = rb + lr;
                int pr = perm[row0s + min(r, rows_here - 1)];
                int eo = (k0 - K1) + ((kb ^ ((r & 7) << 4)) >> 1);
                uint2 u = *reinterpret_cast<const uint2*>(hb8 + (size_t)pr * C + eo);
                float d[8];
                e4m3x4_to_f32(u.x, d); e4m3x4_to_f32(u.y, d + 4);
                ushort8v o;
#pragma unroll
                for (int i = 0; i < 8; i++) o[i] = f2b(d[i]);
                *reinterpret_cast<ushort8v*>(&ldsA[rb * 128 + lane * 16]) = o;
            }
        }
#pragma unroll
        for (int c2 = 0; c2 < BNF / 32; ++c2) {
            int rb = (wid * (BNF / 32) + c2) * 8;
            int r = rb + lr;
            const char* rowp = (const char*)(BtG + (size_t)(col0 + r) * K) + kB;
            gl2lds16(rowp + (kb ^ ((r & 7) << 4)), &ldsB[rb * 128]);
        }
        __syncthreads();
#pragma unroll
        for (int kc = 0; kc < 2; kc++) {
            int kb2 = kc * 64 + (lane >> 4) * 16;
            bf16x8 af[FM], bfr[FN];
#pragma unroll
            for (int m = 0; m < FM; m++) {
                int r = wrow + m * 16 + (lane & 15);
                af[m] = *reinterpret_cast<const bf16x8*>(&ldsA[r * 128 + (kb2 ^ ((r & 7) << 4))]);
            }
#pragma unroll
            for (int n = 0; n < FN; n++) {
                int r = wcol + n * 16 + (lane & 15);
                bfr[n] = *reinterpret_cast<const bf16x8*>(&ldsB[r * 128 + (kb2 ^ ((r & 7) << 4))]);
            }
#pragma unroll
            for (int m = 0; m < FM; m++)
#pragma unroll
                for (int n = 0; n < FN; n++)
                    acc[m][n] = __builtin_amdgcn_mfma_f32_16x16x32_bf16(af[m], bfr[n], acc[m][n], 0, 0, 0);
        }
        __syncthreads();
    }

#pragma unroll
    for (int m = 0; m < FM; m++) {
        int rlb = wrow + m * 16 + (lane >> 4) * 4;
#pragma unroll
        for (int n = 0; n < FN; n++) {
            int col = col0 + wcol + n * 16 + (lane & 15);
            if (col >= Nreal) continue;
            f32x4 v = acc[m][n];
#pragma unroll
            for (int j = 0; j < 4; j++) {
                int rl = rlb + j;
                if (rl >= rows_here) continue;
                int orig_row = perm[row0s + rl];
                float xv = v[j] + rootb[g * Nreal + col];
                if (RELU) xv = fmaxf(xv, 0.f);
                if (OUTF32) outf[(size_t)orig_row * Nreal + col] = xv;
                else        outf8[(size_t)orig_row * Nreal + col] = (unsigned char)f2e4m3(xv);
            }
        }
    }
}

// ---------------- in-place log_softmax over rows of N cols ------------------
__global__ void k_logsm(float* __restrict__ out, int M, int N)
{
    int row = blockIdx.x * 4 + (threadIdx.x >> 6);
    if (row >= M) return;
    int lane = threadIdx.x & 63;
    float* p = out + (size_t)row * N;
    float mx = -3.4e38f;
    for (int c = lane; c < N; c += 64) mx = fmaxf(mx, p[c]);
#pragma unroll
    for (int o = 32; o > 0; o >>= 1) mx = fmaxf(mx, __shfl_xor(mx, o));
    float s = 0.f;
    for (int c = lane; c < N; c += 64) s += expf(p[c] - mx);
#pragma unroll
    for (int o = 32; o > 0; o >>= 1) s += __shfl_xor(s, o);
    float lse = mx + logf(s);
    for (int c = lane; c < N; c += 64) p[c] -= lse;
}

extern "C" void kernel_launch(void* const* d_in, const int* in_sizes, int n_in,
                              void* d_out, int out_size, void* d_ws, size_t ws_size,
                              hipStream_t stream)
{
    const int*   n_id   = (const int*)d_in[0];
    const float* x0     = (const float*)d_in[1];
    const int*   src0   = (const int*)d_in[2];
    const int*   dst0   = (const int*)d_in[3];
    const int*   eid0   = (const int*)d_in[4];
    const int*   src1   = (const int*)d_in[5];
    const int*   dst1   = (const int*)d_in[6];
    const int*   eid1   = (const int*)d_in[7];
    const int*   etype  = (const int*)d_in[8];
    const int*   ntype  = (const int*)d_in[9];
    const int*   lidx   = (const int*)d_in[10];
    const float* emb1   = (const float*)d_in[11];
    const float* emb2   = (const float*)d_in[12];
    const float* emb3   = (const float*)d_in[13];
    const float* relW0  = (const float*)d_in[14];
    const float* rootW0 = (const float*)d_in[15];
    const float* rootb0 = (const float*)d_in[16];
    const float* relW1  = (const float*)d_in[17];
    const float* rootW1 = (const float*)d_in[18];
    const float* rootb1 = (const float*)d_in[19];
    float* out = (float*)d_out;

    const int E0 = in_sizes[2];
    const int E1 = in_sizes[5];
    const int Etot = E0 + E1;
    const int nET = in_sizes[8];
    constexpr int K0s  = kET * kCIN + kCIN;    // 768
    constexpr int K1s  = kET * kHID + kHID;    // 1536
    constexpr int Npad0 = 256;
    constexpr int Npad1 = 384;

    char* ws = (char*)d_ws;
    size_t off = 0;
    auto alloc = [&](size_t bytes) -> void* {
        void* p = ws + off;
        off = (off + bytes + 255) & ~(size_t)255;
        return p;
    };
    unsigned short* h0b   = (unsigned short*)alloc((size_t)kN1 * kCIN * 2);   // only rows < kN1
    unsigned char*  h0f8  = (unsigned char*)alloc((size_t)kN0 * kCIN);
    int*            nt0   = (int*)alloc((size_t)kN0 * 4);
    unsigned short* meanb = (unsigned short*)alloc((size_t)kNSEG0 * kCIN * 2); // >= NSEG1*HID
    int*            cnt    = (int*)alloc((size_t)kNSEG * 4);
    int*            starts = (int*)alloc((size_t)kNSEG * 4);
    int*            cnts2d = (int*)alloc((size_t)kNBin * kNBLK * 4);
    int*            offs2d = (int*)alloc((size_t)kNBin * kNBLK * 4);
    int*            blksum = (int*)alloc(1024 * 4);
    unsigned int*   pairs  = (unsigned int*)alloc((size_t)Etot * 4);
    int*            order  = (int*)alloc((size_t)Etot * 4);
    int*            seg32  = (int*)alloc((size_t)Etot * 4);
    unsigned char*  et8    = (unsigned char*)alloc((size_t)nET);
    unsigned char*  h1f8  = (unsigned char*)alloc((size_t)kN1 * kHID);
    unsigned short* Bt0T  = (unsigned short*)alloc((size_t)kNT * Npad0 * K0s * 2);
    unsigned short* Bt1T  = (unsigned short*)alloc((size_t)kNT * Npad1 * K1s * 2);
    int*            perm0  = (int*)alloc((size_t)kN1 * 4);
    int*            goff0  = (int*)alloc(8 * 4);
    int*            perm1  = (int*)alloc((size_t)kN2 * 4);
    int*            goff1  = (int*)alloc(8 * 4);
    int*            ntcnts = (int*)alloc(1024 * 4);
    int*            ntoffs = (int*)alloc(1024 * 4);

    // ---- weight prep + etype compress (one kernel) ----
    constexpr int TPREP = kNT * Npad0 * K0s + kNT * Npad1 * K1s;
    int prep_total = TPREP + nET;
    k_prep<<<(prep_total + 255) / 256, 256, 0, stream>>>(relW0, rootW0, Bt0T, relW1, rootW1, Bt1T,
                                                         etype, et8, nET);

    // ---- fused: input gather | edge codes + bin hist | nt hist ----
    k_bincnt<<<kGB + kNBLK + 2 * kSB, 1024, 0, stream>>>(
        dst0, eid0, E0, dst1, eid1, E1, et8, cnts2d, seg32,
        n_id, ntype, ntcnts, x0, emb1, emb2, emb3, lidx, h0b, h0f8, nt0);

    int nscan = kNBin * kNBLK;
    int nblk = (nscan + 1023) / 1024;
    k_scan1<<<nblk, 1024, 0, stream>>>(cnts2d, offs2d, blksum, nscan);
    k_scan2<<<2, 1024, 0, stream>>>(blksum, nblk, ntcnts, ntoffs, goff0, goff1);
    k_binplace<<<kNBLK + 2 * kSB, 1024, 0, stream>>>(src0, E0, src1, E1, seg32,
                                                     offs2d, blksum, pairs, nt0, ntoffs, perm0, perm1);

    // ---- fused per-bin scatter + layer-0 segment mean ----
    k_binseg<<<kNBin, 512, 0, stream>>>(offs2d, blksum, Etot, pairs, order, starts, cnt,
                                        h0f8, meanb);

    // ---- layer 0 GEMM: 2 col-blocks, XCD-chunk-paired; h1 as fp8 ----
    int g0 = (kN1 / 64 + 4) * 2;
    k_gemm_sorted<kCIN, 64, 128, 2, 2, 2, 1, 0, 0><<<g0, 256, 0, stream>>>(
        kN1, kHID, Npad0 * K0s, meanb, h0b, nullptr, Bt0T, rootb0, perm0, goff0, nullptr, h1f8);

    // ---- layer 1: segreduce from persisted CSR, then GEMM ----
    k_segreduce8<kHID><<<(kNSEG1 + 15) / 16, 256, 0, stream>>>(starts + kNSEG0, cnt + kNSEG0, order, h1f8, meanb, kNSEG1);
    int g1 = (kN2 / 64 + 5) * 3;
    k_gemm_sorted<kHID, 64, 128, 3, 2, 2, 0, 1, 1><<<g1, 256, 0, stream>>>(
        kN2, kOUT, Npad1 * K1s, meanb, nullptr, h1f8, Bt1T, rootb1, perm1, goff1, out, nullptr);

    k_logsm<<<(kN2 + 3) / 4, 256, 0, stream>>>(out, kN2, kOUT);
}

// Round 19
// 210.869 us; speedup vs baseline: 1.0386x; 1.0386x over previous
//
#include <hip/hip_runtime.h>
#include <hip/hip_bf16.h>
#include <cmath>

constexpr int kCIN = 128, kHID = 256, kOUT = 349;
constexpr int kNT = 4, kET = 5;
constexpr int kN0 = 120000, kN1 = 40000, kN2 = 10000;
constexpr int kNSEG0 = kN1 * kET;   // 200000
constexpr int kNSEG1 = kN2 * kET;   // 50000
constexpr int kNSEG = kNSEG0 + kNSEG1;  // 250000

constexpr int kBinSegs = 512;                               // segments per bin
constexpr int kNBin0 = (kNSEG0 + kBinSegs - 1) / kBinSegs;  // 391
constexpr int kNBin1 = (kNSEG1 + kBinSegs - 1) / kBinSegs;  // 98
constexpr int kNBin  = kNBin0 + kNBin1;                     // 489
constexpr int kNBLK  = 256;                                 // partition blocks
constexpr int kSB    = 128;                                 // sort blocks per layer
constexpr int kGB    = (kN0 + 127) / 128;                   // gather blocks (128 rows/blk)
constexpr int kBinCap = 8192;                               // max edges/bin (validated r5/6)

typedef __bf16 bf16x8 __attribute__((ext_vector_type(8)));
typedef float f32x4 __attribute__((ext_vector_type(4)));
typedef float f32x2v __attribute__((ext_vector_type(2)));
typedef unsigned short ushort8v __attribute__((ext_vector_type(8)));

__device__ __forceinline__ unsigned short f2b(float f) {
    unsigned int b = __float_as_uint(f);
    unsigned int r = (b + 0x7FFFu + ((b >> 16) & 1u)) >> 16;
    return (unsigned short)r;
}
__device__ __forceinline__ float b2f(unsigned short u) {
    return __uint_as_float((unsigned int)u << 16);
}
__device__ __forceinline__ void gl2lds16(const void* g, void* l) {
    __builtin_amdgcn_global_load_lds(
        (const __attribute__((address_space(1))) void*)g,
        (__attribute__((address_space(3))) void*)l, 16, 0, 0);
}

// ---- fp8 e4m3fn helpers (HW cvt when available, manual fallback) -----------
__device__ __forceinline__ unsigned int f2e4m3(float f) {
#if __has_builtin(__builtin_amdgcn_cvt_pk_fp8_f32)
    return (unsigned int)(__builtin_amdgcn_cvt_pk_fp8_f32(f, f, 0, false) & 0xFF);
#else
    unsigned int sb = (__float_as_uint(f) >> 31) << 7;
    float m = fminf(fabsf(f), 448.f);
    unsigned int code;
    if (m < 0.015625f) {
        code = (unsigned int)__float2int_rn(m * 512.f);   // subnormal (incl. boundary)
    } else {
        unsigned int b = __float_as_uint(m);
        b = b + 0x7FFFF + ((b >> 20) & 1);                // RNE at 3-bit mantissa
        int e8 = (int)(b >> 23) - 120;
        if (e8 > 15) code = 0x7E;                          // saturate 448
        else code = ((unsigned int)e8 << 3) | ((b >> 20) & 7);
    }
    return sb | code;
#endif
}

__device__ __forceinline__ void e4m3x4_to_f32(unsigned int u, float* o4) {
#if __has_builtin(__builtin_amdgcn_cvt_pk_f32_fp8)
    f32x2v a = __builtin_amdgcn_cvt_pk_f32_fp8(u, false);
    f32x2v b = __builtin_amdgcn_cvt_pk_f32_fp8(u, true);
    o4[0] = a[0]; o4[1] = a[1]; o4[2] = b[0]; o4[3] = b[1];
#else
#pragma unroll
    for (int i = 0; i < 4; i++) {
        unsigned int c = (u >> (8 * i)) & 0xFF;
        unsigned int s = c >> 7, e = (c >> 3) & 15, mm = c & 7;
        float v;
        if (e == 0) v = (float)mm * 0.001953125f;
        else        v = __uint_as_float((e + 120u) << 23 | mm << 20);
        o4[i] = s ? -v : v;
    }
#endif
}

// ---------------- weight prep (both layers) + etype->u8, one kernel ---------
__global__ void k_prep(const float* __restrict__ relW0, const float* __restrict__ rootW0,
                       unsigned short* __restrict__ Bt0T,
                       const float* __restrict__ relW1, const float* __restrict__ rootW1,
                       unsigned short* __restrict__ Bt1T,
                       const int* __restrict__ etype, unsigned char* __restrict__ et8, int nET)
{
    constexpr int T0 = kNT * 256 * 768;
    constexpr int T1 = kNT * 384 * 1536;
    constexpr int TP = T0 + T1;
    int i = blockIdx.x * 256 + threadIdx.x;
    if (i < T0) {
        int g = i / (256 * 768);
        int rem = i - g * (256 * 768);
        int col = rem / 768;
        int k = rem - col * 768;
        float v = (k < 640) ? relW0[(size_t)k * 256 + col]
                            : rootW0[((size_t)g * 128 + (k - 640)) * 256 + col];
        Bt0T[i] = f2b(v);
    } else if (i < TP) {
        int ii = i - T0;
        int g = ii / (384 * 1536);
        int rem = ii - g * (384 * 1536);
        int col = rem / 1536;
        int k = rem - col * 1536;
        float v = 0.f;
        if (col < kOUT) v = (k < 1280) ? relW1[(size_t)k * kOUT + col]
                                       : rootW1[((size_t)g * 256 + (k - 1280)) * kOUT + col];
        Bt1T[ii] = f2b(v);
    } else {
        int k = i - TP;
        if (k < nET) et8[k] = (unsigned char)etype[k];
    }
}

// ---------------- fused pass A: edge seg-codes + bin hist | nt hist | gather -
// Edge-hist blocks FIRST (longest jobs) so they start in the first wave.
__global__ __launch_bounds__(1024) void k_bincnt(
    const int* __restrict__ dst0, const int* __restrict__ eid0, int E0,
    const int* __restrict__ dst1, const int* __restrict__ eid1, int E1,
    const unsigned char* __restrict__ et8, int* __restrict__ cnts2d,
    int* __restrict__ seg32,
    const int* __restrict__ n_id, const int* __restrict__ ntype, int* __restrict__ ntcnts,
    const float* __restrict__ x0, const float* __restrict__ e1f,
    const float* __restrict__ e2f, const float* __restrict__ e3f,
    const int* __restrict__ lidx,
    unsigned short* __restrict__ h0b, unsigned char* __restrict__ h0f8,
    int* __restrict__ nt0)
{
    __shared__ int h[kNBin];
    const int tid = threadIdx.x;
    if (blockIdx.x < kNBLK) {
        for (int k = tid; k < kNBin; k += 1024) h[k] = 0;
        __syncthreads();
        int Etot = E0 + E1;
        int chunk = (Etot + kNBLK - 1) / kNBLK;
        int lo = blockIdx.x * chunk;
        int hi = min(lo + chunk, Etot);
        for (int i = lo + tid; i < hi; i += 1024) {
            int c;
            if (i < E0) c = dst0[i] * kET + (int)et8[eid0[i]];
            else { int e = i - E0; c = kNBin0 * kBinSegs + dst1[e] * kET + (int)et8[eid1[e]]; }
            seg32[i] = c;
            atomicAdd(&h[c >> 9], 1);
        }
        __syncthreads();
        for (int k = tid; k < kNBin; k += 1024) cnts2d[(size_t)k * kNBLK + blockIdx.x] = h[k];
    } else if (blockIdx.x < kNBLK + 2 * kSB) {
        int b = blockIdx.x - kNBLK;
        int layer = b >= kSB;
        int blk = b - layer * kSB;
        int M = layer ? kN2 : kN1;
        if (tid < 4) h[tid] = 0;
        __syncthreads();
        int chunk = (M + kSB - 1) / kSB;
        int lo = blk * chunk, hi = min(lo + chunk, M);
        for (int i = lo + tid; i < hi; i += 1024) atomicAdd(&h[ntype[n_id[i]]], 1);
        __syncthreads();
        if (tid < 4) ntcnts[(layer * 4 + tid) * kSB + blk] = h[tid];
    } else {
        // input gather: 128 rows per block, four rows per lane-group (MLP x4)
        int base = (blockIdx.x - kNBLK - 2 * kSB) * 128;
        int lane = tid & 31;
        int grp = tid >> 5;
        int r[4];
        const float* tab[4];
        int idx[4], ntv[4];
        bool ok[4];
#pragma unroll
        for (int k = 0; k < 4; k++) {
            r[k] = base + grp + k * 32;
            ok[k] = r[k] < kN0;
            int rr = ok[k] ? r[k] : kN0 - 1;
            int gid = n_id[rr];
            int nt = ntype[gid];
            int li = lidx[gid];
            const float* tb; int rows;
            if (nt == 0)      { tb = x0;  rows = 100000; }
            else if (nt == 1) { tb = e1f; rows = 50000; }
            else if (nt == 2) { tb = e2f; rows = 50000; }
            else              { tb = e3f; rows = 50000; }
            tab[k] = tb;
            idx[k] = li < rows ? li : rows - 1;
            ntv[k] = nt;
        }
        float4 v[4];
#pragma unroll
        for (int k = 0; k < 4; k++)
            v[k] = reinterpret_cast<const float4*>(tab[k] + (size_t)idx[k] * kCIN)[lane];
#pragma unroll
        for (int k = 0; k < 4; k++) {
            if (!ok[k]) continue;
            unsigned int q = f2e4m3(v[k].x) | (f2e4m3(v[k].y) << 8)
                           | (f2e4m3(v[k].z) << 16) | (f2e4m3(v[k].w) << 24);
            reinterpret_cast<unsigned int*>(h0f8 + (size_t)r[k] * kCIN)[lane] = q;
            if (r[k] < kN1) {   // bf16 copy only needed for gemm0's root slab
                ushort4 o;
                o.x = f2b(v[k].x); o.y = f2b(v[k].y); o.z = f2b(v[k].z); o.w = f2b(v[k].w);
                reinterpret_cast<ushort4*>(h0b + (size_t)r[k] * kCIN)[lane] = o;
            }
            if (lane == 0) nt0[r[k]] = ntv[k];
        }
    }
}

// ---------------- scans ------------------------------------------------------
__global__ void k_scan1(const int* __restrict__ cnt, int* __restrict__ excl,
                        int* __restrict__ blksum, int n)
{
    __shared__ int sm[1024];
    int i = blockIdx.x * 1024 + threadIdx.x;
    int v = (i < n) ? cnt[i] : 0;
    sm[threadIdx.x] = v;
    __syncthreads();
    for (int off = 1; off < 1024; off <<= 1) {
        int t = (threadIdx.x >= off) ? sm[threadIdx.x - off] : 0;
        __syncthreads();
        sm[threadIdx.x] += t;
        __syncthreads();
    }
    if (i < n) excl[i] = sm[threadIdx.x] - v;
    if (threadIdx.x == 1023) blksum[blockIdx.x] = sm[1023];
}

// block 0: scan blksum; block 1: segmented scan of ntcnts -> ntoffs + goff
__global__ __launch_bounds__(1024) void k_scan2(
    int* __restrict__ blksum, int nblk,
    const int* __restrict__ ntcnts, int* __restrict__ ntoffs,
    int* __restrict__ goff0, int* __restrict__ goff1)
{
    __shared__ int sm[1024];
    int tid = threadIdx.x;
    if (blockIdx.x == 0) {
        int v = (tid < nblk) ? blksum[tid] : 0;
        sm[tid] = v;
        __syncthreads();
        for (int off = 1; off < 1024; off <<= 1) {
            int t = (tid >= off) ? sm[tid - off] : 0;
            __syncthreads();
            sm[tid] += t;
            __syncthreads();
        }
        if (tid < nblk) blksum[tid] = sm[tid] - v;
    } else {
        int v = ntcnts[tid];
        sm[tid] = v;
        __syncthreads();
        for (int off = 1; off < 512; off <<= 1) {
            int t = 0;
            if ((tid & 511) >= off) t = sm[tid - off];
            __syncthreads();
            sm[tid] += t;
            __syncthreads();
        }
        int excl = sm[tid] - v;
        ntoffs[tid] = excl;
        if ((tid & 127) == 0) {
            int layer = tid >> 9;
            int t = (tid >> 7) & 3;
            if (layer == 0) goff0[t] = excl; else goff1[t] = excl;
        }
        if (tid == 0) { goff0[4] = kN1; goff1[4] = kN2; }
    }
}

// ---------------- pass B: place edges (seg32 streaming) + nt place ----------
__global__ __launch_bounds__(1024) void k_binplace(
    const int* __restrict__ src0, int E0,
    const int* __restrict__ src1, int E1,
    const int* __restrict__ seg32,
    const int* __restrict__ offs2d, const int* __restrict__ blksum,
    unsigned int* __restrict__ pairs,
    const int* __restrict__ nt0, const int* __restrict__ ntoffs,
    int* __restrict__ perm0, int* __restrict__ perm1)
{
    __shared__ int cur[kNBin];
    const int tid = threadIdx.x;
    if (blockIdx.x < kNBLK) {
        for (int k = tid; k < kNBin; k += 1024) {
            size_t li = (size_t)k * kNBLK + blockIdx.x;
            cur[k] = offs2d[li] + blksum[li >> 10];
        }
        __syncthreads();
        int Etot = E0 + E1;
        int chunk = (Etot + kNBLK - 1) / kNBLK;
        int lo = blockIdx.x * chunk;
        int hi = min(lo + chunk, Etot);
        for (int i = lo + tid; i < hi; i += 1024) {
            int c = seg32[i];
            int s = (i < E0) ? src0[i] : src1[i - E0];
            unsigned int pay = (unsigned int)s | ((unsigned int)(c & (kBinSegs - 1)) << 17);
            int p = atomicAdd(&cur[c >> 9], 1);
            pairs[p] = pay;
        }
    } else {
        int b = blockIdx.x - kNBLK;
        int layer = b >= kSB;
        int blk = b - layer * kSB;
        int M = layer ? kN2 : kN1;
        int* perm = layer ? perm1 : perm0;
        if (tid < 4) cur[tid] = ntoffs[(layer * 4 + tid) * kSB + blk];
        __syncthreads();
        int chunk = (M + kSB - 1) / kSB;
        int lo = blk * chunk, hi = min(lo + chunk, M);
        for (int i = lo + tid; i < hi; i += 1024) {
            int p = atomicAdd(&cur[nt0[i]], 1);
            perm[p] = i;
        }
    }
}

// ---------------- fused per-bin scatter + layer-0 segment-mean --------------
__global__ __launch_bounds__(512) void k_binseg(
    const int* __restrict__ offs2d, const int* __restrict__ blksum, int Etot,
    const unsigned int* __restrict__ pairs,
    int* __restrict__ order, int* __restrict__ starts, int* __restrict__ cnt,
    const unsigned char* __restrict__ h0f8, unsigned short* __restrict__ meanb)
{
    __shared__ int h[kBinSegs];
    __shared__ int sc[kBinSegs];
    __shared__ int cur[kBinSegs];
    __shared__ int ordl[kBinCap];
    const int bin = blockIdx.x;
    const int tid = threadIdx.x;
    size_t bi = (size_t)bin * kNBLK;
    const int base = offs2d[bi] + blksum[bi >> 10];
    int end = Etot;
    if (bin + 1 < kNBin) {
        size_t ei = (size_t)(bin + 1) * kNBLK;
        end = offs2d[ei] + blksum[ei >> 10];
    }
    const int c = end - base;
    const unsigned int* pp = pairs + base;

    h[tid] = 0;
    __syncthreads();
    for (int j = tid; j < c; j += 512) atomicAdd(&h[pp[j] >> 17], 1);
    __syncthreads();
    sc[tid] = h[tid];
    __syncthreads();
    for (int off = 1; off < kBinSegs; off <<= 1) {
        int t = (tid >= off) ? sc[tid - off] : 0;
        __syncthreads();
        sc[tid] += t;
        __syncthreads();
    }
    cur[tid] = sc[tid] - h[tid];
    __syncthreads();
    for (int j = tid; j < c; j += 512) {
        unsigned int u = pp[j];
        int sl = (int)(u >> 17);
        int p = atomicAdd(&cur[sl], 1);
        if (p < kBinCap) ordl[p] = (int)(u & 0x1FFFFu);
    }
    __syncthreads();

    if (bin < kNBin0) {
        // layer-0: fp8 gather-mean straight from LDS order
        int seg_base = bin * kBinSegs;
        int seglim = min(kBinSegs, kNSEG0 - seg_base);
#pragma unroll 1
        for (int pass = 0; pass < 8; ++pass) {
            int srel = (tid >> 3) + pass * 64;
            if (srel >= seglim) continue;
            int lane = tid & 7;                 // 8 lanes x 16B = 128 fp8
            int st = sc[srel] - h[srel];
            int n = h[srel];
            const unsigned char* hp = h0f8 + (size_t)lane * 16;
            float a0[16], a1[16];
#pragma unroll
            for (int i = 0; i < 16; i++) { a0[i] = 0.f; a1[i] = 0.f; }
            int j = 0;
            for (; j + 2 <= n; j += 2) {
                int s0 = ordl[st + j];
                int s1 = ordl[st + j + 1];
                uint4 u0 = *reinterpret_cast<const uint4*>(hp + (size_t)s0 * kCIN);
                uint4 u1 = *reinterpret_cast<const uint4*>(hp + (size_t)s1 * kCIN);
                float d[16];
                e4m3x4_to_f32(u0.x, d); e4m3x4_to_f32(u0.y, d + 4);
                e4m3x4_to_f32(u0.z, d + 8); e4m3x4_to_f32(u0.w, d + 12);
#pragma unroll
                for (int i = 0; i < 16; i++) a0[i] += d[i];
                e4m3x4_to_f32(u1.x, d); e4m3x4_to_f32(u1.y, d + 4);
                e4m3x4_to_f32(u1.z, d + 8); e4m3x4_to_f32(u1.w, d + 12);
#pragma unroll
                for (int i = 0; i < 16; i++) a1[i] += d[i];
            }
            if (j < n) {
                int s0 = ordl[st + j];
                uint4 u0 = *reinterpret_cast<const uint4*>(hp + (size_t)s0 * kCIN);
                float d[16];
                e4m3x4_to_f32(u0.x, d); e4m3x4_to_f32(u0.y, d + 4);
                e4m3x4_to_f32(u0.z, d + 8); e4m3x4_to_f32(u0.w, d + 12);
#pragma unroll
                for (int i = 0; i < 16; i++) a0[i] += d[i];
            }
            float scv = 1.0f / fmaxf((float)n, 1.0f);
            ushort8v o0, o1;
#pragma unroll
            for (int i = 0; i < 8; i++) {
                o0[i] = f2b((a0[i] + a1[i]) * scv);
                o1[i] = f2b((a0[i + 8] + a1[i + 8]) * scv);
            }
            unsigned short* mp = meanb + (size_t)(seg_base + srel) * kCIN + lane * 16;
            *reinterpret_cast<ushort8v*>(mp) = o0;
            *reinterpret_cast<ushort8v*>(mp + 8) = o1;
        }
    } else {
        // layer-1: persist CSR for segreduce1 (runs after gemm0)
        int seg_rel = (bin - kNBin0) * kBinSegs;
        int abs_base = kNSEG0 + seg_rel;
        int seglim = kNSEG1 - seg_rel;
        if (tid < seglim) {
            starts[abs_base + tid] = base + (sc[tid] - h[tid]);
            cnt[abs_base + tid] = h[tid];
        }
        for (int j = tid; j < c; j += 512) order[base + j] = ordl[j];
    }
}

// ---------------- layer-1 segment-mean: fp8 gather (16B/lane) ---------------
template<int C>
__global__ __launch_bounds__(256) void k_segreduce8(
    const int* __restrict__ starts, const int* __restrict__ cnt,
    const int* __restrict__ order, const unsigned char* __restrict__ h8,
    unsigned short* __restrict__ mean, int nseg)
{
    constexpr int L = C / 16;
    constexpr int SPB = 256 / L;
    int sidx = blockIdx.x * SPB + threadIdx.x / L;
    if (sidx >= nseg) return;
    int lane = threadIdx.x % L;
    int st = starts[sidx];
    int n = cnt[sidx];
    const unsigned char* hp = h8 + (size_t)lane * 16;
    float a0[16], a1[16];
#pragma unroll
    for (int i = 0; i < 16; i++) { a0[i] = 0.f; a1[i] = 0.f; }
    int j = 0;
    for (; j + 2 <= n; j += 2) {
        int s0 = order[st + j + 0];
        int s1 = order[st + j + 1];
        uint4 u0 = *reinterpret_cast<const uint4*>(hp + (size_t)s0 * C);
        uint4 u1 = *reinterpret_cast<const uint4*>(hp + (size_t)s1 * C);
        float d[16];
        e4m3x4_to_f32(u0.x, d); e4m3x4_to_f32(u0.y, d + 4);
        e4m3x4_to_f32(u0.z, d + 8); e4m3x4_to_f32(u0.w, d + 12);
#pragma unroll
        for (int i = 0; i < 16; i++) a0[i] += d[i];
        e4m3x4_to_f32(u1.x, d); e4m3x4_to_f32(u1.y, d + 4);
        e4m3x4_to_f32(u1.z, d + 8); e4m3x4_to_f32(u1.w, d + 12);
#pragma unroll
        for (int i = 0; i < 16; i++) a1[i] += d[i];
    }
    if (j < n) {
        int s0 = order[st + j];
        uint4 u0 = *reinterpret_cast<const uint4*>(hp + (size_t)s0 * C);
        float d[16];
        e4m3x4_to_f32(u0.x, d); e4m3x4_to_f32(u0.y, d + 4);
        e4m3x4_to_f32(u0.z, d + 8); e4m3x4_to_f32(u0.w, d + 12);
#pragma unroll
        for (int i = 0; i < 16; i++) a0[i] += d[i];
    }
    float sc = 1.0f / fmaxf((float)n, 1.0f);
    ushort8v o0, o1;
#pragma unroll
    for (int i = 0; i < 8; i++) {
        o0[i] = f2b((a0[i] + a1[i]) * sc);
        o1[i] = f2b((a0[i + 8] + a1[i + 8]) * sc);
    }
    unsigned short* mp = mean + (size_t)sidx * C + lane * 16;
    *reinterpret_cast<ushort8v*>(mp) = o0;
    *reinterpret_cast<ushort8v*>(mp + 8) = o1;
}

// ---------------- sorted MFMA GEMM, NCB col-blocks, XCD-chunked blocks ------
template<int C, int BM, int BNF, int NCB, int WR, int WC, int RELU, int AF8, int OUTF32>
__global__ __launch_bounds__(256) void k_gemm_sorted(
    int M, int Nreal, int NpadK,
    const unsigned short* __restrict__ meanb,
    const unsigned short* __restrict__ hb,
    const unsigned char* __restrict__ hb8,
    const unsigned short* __restrict__ BtT,
    const float* __restrict__ rootb,
    const int* __restrict__ perm, const int* __restrict__ goff,
    float* __restrict__ outf, unsigned char* __restrict__ outf8)
{
    constexpr int K1 = kET * C;     // mean region
    constexpr int K  = K1 + C;      // + dense root slab
    constexpr int FM = BM / (16 * WR);
    constexpr int FN = BNF / (16 * WC);
    __shared__ __align__(16) char ldsA[BM * 128];
    __shared__ __align__(16) char ldsB[BNF * 128];

    int nwg = gridDim.x;
    int orig = blockIdx.x;
    int q = nwg >> 3, r8 = nwg & 7, x8 = orig & 7;
    int logical = (x8 < r8 ? x8 * (q + 1) : r8 * (q + 1) + (x8 - r8) * q) + (orig >> 3);
    int colb = logical % NCB;
    int t = logical / NCB;

    int g, row0s = 0, gend = 0;
    {
        int gs[5] = {goff[0], goff[1], goff[2], goff[3], goff[4]};
        int tb = 0;
        for (g = 0; g < 4; ++g) {
            int cg = gs[g + 1] - gs[g];
            int ntl = (cg + BM - 1) / BM;
            if (t < tb + ntl) { row0s = gs[g] + (t - tb) * BM; gend = gs[g + 1]; break; }
            tb += ntl;
        }
        if (g == 4) return;   // padding tile
    }
    const int rows_here = min(BM, gend - row0s);
    const unsigned short* BtG = BtT + (size_t)g * NpadK;

    const int tid = threadIdx.x;
    const int col0 = colb * BNF;
    const int wid = tid >> 6, lane = tid & 63;
    const int wrow = (wid / WC) * (BM / WR);
    const int wcol = (wid % WC) * (BNF / WC);
    const int lr = lane >> 3;
    const int kb = (lane & 7) * 16;

    f32x4 acc[FM][FN] = {};

    for (int k0 = 0; k0 < K; k0 += 64) {
        const bool inMean = (k0 < K1);
        const size_t kB = (size_t)k0 * 2;
        if (!AF8 || inMean) {
#pragma unroll
            for (int c2 = 0; c2 < BM / 32; ++c2) {
                int rb = (wid * (BM / 32) + c2) * 8;
                int r = rb + lr;
                int pr = perm[row0s + min(r, rows_here - 1)];
                const char* rowp = inMean
                    ? (const char*)(meanb + (size_t)pr * K1) + kB
                    : (const char*)(hb + (size_t)pr * C) + (kB - (size_t)K1 * 2);
                gl2lds16(rowp + (kb ^ ((r & 7) << 4)), &ldsA[rb * 128]);
            }
        } else {
#pragma unroll
            for (int c2 = 0; c2 < BM / 32; ++c2) {
                int rb = (wid * (BM / 32) + c2) * 8;
                int r = rb + lr;
                int pr = perm[row0s + min(r, rows_here - 1)];
                int eo = (k0 - K1) + ((kb ^ ((r & 7) << 4)) >> 1);
                uint2 u = *reinterpret_cast<const uint2*>(hb8 + (size_t)pr * C + eo);
                float d[8];
                e4m3x4_to_f32(u.x, d); e4m3x4_to_f32(u.y, d + 4);
                ushort8v o;
#pragma unroll
                for (int i = 0; i < 8; i++) o[i] = f2b(d[i]);
                *reinterpret_cast<ushort8v*>(&ldsA[rb * 128 + lane * 16]) = o;
            }
        }
#pragma unroll
        for (int c2 = 0; c2 < BNF / 32; ++c2) {
            int rb = (wid * (BNF / 32) + c2) * 8;
            int r = rb + lr;
            const char* rowp = (const char*)(BtG + (size_t)(col0 + r) * K) + kB;
            gl2lds16(rowp + (kb ^ ((r & 7) << 4)), &ldsB[rb * 128]);
        }
        __syncthreads();
#pragma unroll
        for (int kc = 0; kc < 2; kc++) {
            int kb2 = kc * 64 + (lane >> 4) * 16;
            bf16x8 af[FM], bfr[FN];
#pragma unroll
            for (int m = 0; m < FM; m++) {
                int r = wrow + m * 16 + (lane & 15);
                af[m] = *reinterpret_cast<const bf16x8*>(&ldsA[r * 128 + (kb2 ^ ((r & 7) << 4))]);
            }
#pragma unroll
            for (int n = 0; n < FN; n++) {
                int r = wcol + n * 16 + (lane & 15);
                bfr[n] = *reinterpret_cast<const bf16x8*>(&ldsB[r * 128 + (kb2 ^ ((r & 7) << 4))]);
            }
#pragma unroll
            for (int m = 0; m < FM; m++)
#pragma unroll
                for (int n = 0; n < FN; n++)
                    acc[m][n] = __builtin_amdgcn_mfma_f32_16x16x32_bf16(af[m], bfr[n], acc[m][n], 0, 0, 0);
        }
        __syncthreads();
    }

#pragma unroll
    for (int m = 0; m < FM; m++) {
        int rlb = wrow + m * 16 + (lane >> 4) * 4;
#pragma unroll
        for (int n = 0; n < FN; n++) {
            int col = col0 + wcol + n * 16 + (lane & 15);
            if (col >= Nreal) continue;
            f32x4 v = acc[m][n];
#pragma unroll
            for (int j = 0; j < 4; j++) {
                int rl = rlb + j;
                if (rl >= rows_here) continue;
                int orig_row = perm[row0s + rl];
                float xv = v[j] + rootb[g * Nreal + col];
                if (RELU) xv = fmaxf(xv, 0.f);
                if (OUTF32) outf[(size_t)orig_row * Nreal + col] = xv;
                else        outf8[(size_t)orig_row * Nreal + col] = (unsigned char)f2e4m3(xv);
            }
        }
    }
}

// ---------------- in-place log_softmax over rows of N cols ------------------
__global__ void k_logsm(float* __restrict__ out, int M, int N)
{
    int row = blockIdx.x * 4 + (threadIdx.x >> 6);
    if (row >= M) return;
    int lane = threadIdx.x & 63;
    float* p = out + (size_t)row * N;
    float mx = -3.4e38f;
    for (int c = lane; c < N; c += 64) mx = fmaxf(mx, p[c]);
#pragma unroll
    for (int o = 32; o > 0; o >>= 1) mx = fmaxf(mx, __shfl_xor(mx, o));
    float s = 0.f;
    for (int c = lane; c < N; c += 64) s += expf(p[c] - mx);
#pragma unroll
    for (int o = 32; o > 0; o >>= 1) s += __shfl_xor(s, o);
    float lse = mx + logf(s);
    for (int c = lane; c < N; c += 64) p[c] -= lse;
}

extern "C" void kernel_launch(void* const* d_in, const int* in_sizes, int n_in,
                              void* d_out, int out_size, void* d_ws, size_t ws_size,
                              hipStream_t stream)
{
    const int*   n_id   = (const int*)d_in[0];
    const float* x0     = (const float*)d_in[1];
    const int*   src0   = (const int*)d_in[2];
    const int*   dst0   = (const int*)d_in[3];
    const int*   eid0   = (const int*)d_in[4];
    const int*   src1   = (const int*)d_in[5];
    const int*   dst1   = (const int*)d_in[6];
    const int*   eid1   = (const int*)d_in[7];
    const int*   etype  = (const int*)d_in[8];
    const int*   ntype  = (const int*)d_in[9];
    const int*   lidx   = (const int*)d_in[10];
    const float* emb1   = (const float*)d_in[11];
    const float* emb2   = (const float*)d_in[12];
    const float* emb3   = (const float*)d_in[13];
    const float* relW0  = (const float*)d_in[14];
    const float* rootW0 = (const float*)d_in[15];
    const float* rootb0 = (const float*)d_in[16];
    const float* relW1  = (const float*)d_in[17];
    const float* rootW1 = (const float*)d_in[18];
    const float* rootb1 = (const float*)d_in[19];
    float* out = (float*)d_out;

    const int E0 = in_sizes[2];
    const int E1 = in_sizes[5];
    const int Etot = E0 + E1;
    const int nET = in_sizes[8];
    constexpr int K0s  = kET * kCIN + kCIN;    // 768
    constexpr int K1s  = kET * kHID + kHID;    // 1536
    constexpr int Npad0 = 256;
    constexpr int Npad1 = 384;

    char* ws = (char*)d_ws;
    size_t off = 0;
    auto alloc = [&](size_t bytes) -> void* {
        void* p = ws + off;
        off = (off + bytes + 255) & ~(size_t)255;
        return p;
    };
    unsigned short* h0b   = (unsigned short*)alloc((size_t)kN1 * kCIN * 2);   // only rows < kN1
    unsigned char*  h0f8  = (unsigned char*)alloc((size_t)kN0 * kCIN);
    int*            nt0   = (int*)alloc((size_t)kN0 * 4);
    unsigned short* meanb = (unsigned short*)alloc((size_t)kNSEG0 * kCIN * 2); // >= NSEG1*HID
    int*            cnt    = (int*)alloc((size_t)kNSEG * 4);
    int*            starts = (int*)alloc((size_t)kNSEG * 4);
    int*            cnts2d = (int*)alloc((size_t)kNBin * kNBLK * 4);
    int*            offs2d = (int*)alloc((size_t)kNBin * kNBLK * 4);
    int*            blksum = (int*)alloc(1024 * 4);
    unsigned int*   pairs  = (unsigned int*)alloc((size_t)Etot * 4);
    int*            order  = (int*)alloc((size_t)Etot * 4);
    int*            seg32  = (int*)alloc((size_t)Etot * 4);
    unsigned char*  et8    = (unsigned char*)alloc((size_t)nET);
    unsigned char*  h1f8  = (unsigned char*)alloc((size_t)kN1 * kHID);
    unsigned short* Bt0T  = (unsigned short*)alloc((size_t)kNT * Npad0 * K0s * 2);
    unsigned short* Bt1T  = (unsigned short*)alloc((size_t)kNT * Npad1 * K1s * 2);
    int*            perm0  = (int*)alloc((size_t)kN1 * 4);
    int*            goff0  = (int*)alloc(8 * 4);
    int*            perm1  = (int*)alloc((size_t)kN2 * 4);
    int*            goff1  = (int*)alloc(8 * 4);
    int*            ntcnts = (int*)alloc(1024 * 4);
    int*            ntoffs = (int*)alloc(1024 * 4);

    // ---- weight prep + etype compress (one kernel) ----
    constexpr int TPREP = kNT * Npad0 * K0s + kNT * Npad1 * K1s;
    int prep_total = TPREP + nET;
    k_prep<<<(prep_total + 255) / 256, 256, 0, stream>>>(relW0, rootW0, Bt0T, relW1, rootW1, Bt1T,
                                                         etype, et8, nET);

    // ---- fused: edge codes + bin hist | nt hist | input gather ----
    k_bincnt<<<kNBLK + 2 * kSB + kGB, 1024, 0, stream>>>(
        dst0, eid0, E0, dst1, eid1, E1, et8, cnts2d, seg32,
        n_id, ntype, ntcnts, x0, emb1, emb2, emb3, lidx, h0b, h0f8, nt0);

    int nscan = kNBin * kNBLK;
    int nblk = (nscan + 1023) / 1024;
    k_scan1<<<nblk, 1024, 0, stream>>>(cnts2d, offs2d, blksum, nscan);
    k_scan2<<<2, 1024, 0, stream>>>(blksum, nblk, ntcnts, ntoffs, goff0, goff1);
    k_binplace<<<kNBLK + 2 * kSB, 1024, 0, stream>>>(src0, E0, src1, E1, seg32,
                                                     offs2d, blksum, pairs, nt0, ntoffs, perm0, perm1);

    // ---- fused per-bin scatter + layer-0 segment mean ----
    k_binseg<<<kNBin, 512, 0, stream>>>(offs2d, blksum, Etot, pairs, order, starts, cnt,
                                        h0f8, meanb);

    // ---- layer 0 GEMM: 2 col-blocks, XCD-chunk-paired; h1 as fp8 ----
    int g0 = (kN1 / 64 + 4) * 2;
    k_gemm_sorted<kCIN, 64, 128, 2, 2, 2, 1, 0, 0><<<g0, 256, 0, stream>>>(
        kN1, kHID, Npad0 * K0s, meanb, h0b, nullptr, Bt0T, rootb0, perm0, goff0, nullptr, h1f8);

    // ---- layer 1: segreduce from persisted CSR, then GEMM ----
    k_segreduce8<kHID><<<(kNSEG1 + 15) / 16, 256, 0, stream>>>(starts + kNSEG0, cnt + kNSEG0, order, h1f8, meanb, kNSEG1);
    int g1 = (kN2 / 64 + 5) * 3;
    k_gemm_sorted<kHID, 64, 128, 3, 2, 2, 0, 1, 1><<<g1, 256, 0, stream>>>(
        kN2, kOUT, Npad1 * K1s, meanb, nullptr, h1f8, Bt1T, rootb1, perm1, goff1, out, nullptr);

    k_logsm<<<(kN2 + 3) / 4, 256, 0, stream>>>(out, kN2, kOUT);
}